// Round 7
// baseline (1081.763 us; speedup 1.0000x reference)
//
#include <hip/hip_runtime.h>
#include <math.h>

// ---- static problem constants ----
#define BZ 8
#define MAXL 5500
#define DD 64
// segment layout:
//   seg0: txt [0,225), img [225,2025)    (src s = L-225)
//   seg1: txt [2025,2250), img [2250,4050) (src s = L-2250+1800)
// attn squares: [0,2025)^2 and [2025,4050)^2

// output offsets (in floats), concatenated in reference return order
#define OFF_LOSS 0
#define OFF_TOK  8
#define OFF_TXT  (8 + BZ * MAXL * DD)          // 2,816,008
#define OFF_IMG  (OFF_TXT + BZ * MAXL)         // 2,860,008
#define OFF_POS  (OFF_IMG + BZ * MAXL)         // 2,904,008
#define OFF_ATTN (OFF_POS + BZ * MAXL * 3)     // 3,036,008  (%4 == 0 -> float4 ok)

// ------------------------------------------------------------------
// attn mask, two-phase:
//   phase 1 (in kernel_launch): hipMemsetAsync zeroes all 968 MB via the
//     runtime's fillBufferAligned path (measured 6.2 TB/s on this buffer).
//   phase 2 (this kernel): write ONLY the 4050 rows/batch that contain
//     ones, as an aligned 2048-float span per row (zero-padded edges so
//     every store is float4-aligned; pads rewrite memset zeros). 265 MB.
// Discriminates code-path vs total-stream-bound theories (see journal).
__global__ __launch_bounds__(256) void ones_kernel(float* __restrict__ attn) {
    int br = blockIdx.x;                 // [0, BZ*4050)
    int r  = br % 4050;
    int b  = br / 4050;
    float* row = attn + ((size_t)b * MAXL + r) * MAXL;
    int lo, hi, base4;
    if (r < 2025) { lo = 0;    hi = 2025; base4 = 0;   }  // span cols [0,2048)
    else          { lo = 2025; hi = 4050; base4 = 504; }  // span cols [2016,4064)
    #pragma unroll
    for (int k = 0; k < 2; k++) {
        int f4 = base4 + k * 256 + threadIdx.x;
        int c  = f4 * 4;
        float4 v;
        v.x = (c + 0 >= lo && c + 0 < hi) ? 1.f : 0.f;
        v.y = (c + 1 >= lo && c + 1 < hi) ? 1.f : 0.f;
        v.z = (c + 2 >= lo && c + 2 < hi) ? 1.f : 0.f;
        v.w = (c + 3 >= lo && c + 3 < hi) ? 1.f : 0.f;
        reinterpret_cast<float4*>(row)[f4] = v;
    }
}

// ------------------------------------------------------------------
// tokens gather + per-block loss partials. 4 tokens per 256-thread block.
__global__ __launch_bounds__(256) void token_kernel(
        const float* __restrict__ input, const float* __restrict__ noise,
        const float* __restrict__ alphas, float* __restrict__ out_tok,
        float* __restrict__ ws_partial) {
    int blk = blockIdx.x;                 // [0, BZ*1375)
    int b = blk / 1375;
    int Lbase = (blk % 1375) * 4;
    int t = threadIdx.x;
    int L = Lbase + (t >> 6);
    int d = t & 63;

    float tok = 0.f, contrib = 0.f;
    int s = -1;
    if (L >= 225 && L < 2025)       s = L - 225;
    else if (L >= 2250 && L < 4050) s = L - 2250 + 1800;
    if (s >= 0) {
        int g  = b * 3600 + s;
        int tf = g / 900;
        int rr = g - tf * 900;
        int hh = rr / 30;
        int ww = rr - hh * 30;
        int c = d & 15, q = (d >> 4) & 1, p = d >> 5;
        int iidx = ((tf * 16 + c) * 60 + (hh * 2 + p)) * 60 + (ww * 2 + q);
        tok = input[iidx];
        float nz  = noise[((size_t)b * MAXL + L) * DD + d];
        float a   = alphas[b];
        float sig = sqrtf(fmaxf(1.f - a * a, 0.f));
        float diff = tok * (a - 1.f) + nz * sig;
        contrib = diff * diff;
    }
    out_tok[((size_t)b * MAXL + L) * DD + d] = tok;

    // wave64 reduce + cross-wave LDS reduce -> one partial per block
    #pragma unroll
    for (int off = 32; off > 0; off >>= 1)
        contrib += __shfl_down(contrib, off, 64);
    __shared__ float lds[4];
    if ((t & 63) == 0) lds[t >> 6] = contrib;
    __syncthreads();
    if (t == 0) ws_partial[blk] = lds[0] + lds[1] + lds[2] + lds[3];
}

// ------------------------------------------------------------------
// txt/img masks + 3d position ids (tiny)
__global__ __launch_bounds__(256) void mask_kernel(float* __restrict__ out) {
    int L = blockIdx.x * 256 + threadIdx.x;
    if (L >= MAXL) return;
    float txt = ((L < 225) || (L >= 2025 && L < 2250)) ? 1.f : 0.f;
    int tloc = -1;
    if (L >= 225 && L < 2025)       tloc = L - 225;
    else if (L >= 2250 && L < 4050) tloc = L - 2250;   // pos ids reset per segment
    float img = (tloc >= 0) ? 1.f : 0.f;
    float pi = -1.f, pj = -1.f, pk = -1.f;
    if (tloc >= 0) {
        int fi = tloc / 900;
        int rr = tloc - fi * 900;
        pi = (float)fi;
        pj = (float)(rr / 30);
        pk = (float)(rr % 30);
    }
    float* txtp = out + OFF_TXT;
    float* imgp = out + OFF_IMG;
    float* posp = out + OFF_POS;
    #pragma unroll
    for (int b = 0; b < BZ; b++) {
        txtp[b * MAXL + L] = txt;
        imgp[b * MAXL + L] = img;
        posp[((size_t)b * MAXL + L) * 3 + 0] = pi;
        posp[((size_t)b * MAXL + L) * 3 + 1] = pj;
        posp[((size_t)b * MAXL + L) * 3 + 2] = pk;
    }
}

// ------------------------------------------------------------------
// final loss: one block per b sums its 1375 block partials
__global__ __launch_bounds__(256) void loss_kernel(
        const float* __restrict__ ws_partial, const float* __restrict__ alphas,
        float* __restrict__ out_loss) {
    int b = blockIdx.x;
    float s = 0.f;
    for (int i = threadIdx.x; i < 1375; i += 256)
        s += ws_partial[b * 1375 + i];
    #pragma unroll
    for (int off = 32; off > 0; off >>= 1)
        s += __shfl_down(s, off, 64);
    __shared__ float lds[4];
    if ((threadIdx.x & 63) == 0) lds[threadIdx.x >> 6] = s;
    __syncthreads();
    if (threadIdx.x == 0) {
        float tot = lds[0] + lds[1] + lds[2] + lds[3];
        float a = alphas[b];
        out_loss[b] = tot / ((1.f - a * a) * (float)(MAXL * DD));
    }
}

extern "C" void kernel_launch(void* const* d_in, const int* in_sizes, int n_in,
                              void* d_out, int out_size, void* d_ws, size_t ws_size,
                              hipStream_t stream) {
    const float* input  = (const float*)d_in[0];   // (1,32,16,60,60)
    const float* noise  = (const float*)d_in[1];   // (8,5500,64)
    const float* alphas = (const float*)d_in[2];   // (8,)
    float* out = (float*)d_out;
    float* ws  = (float*)d_ws;                     // 11,000 floats used

    // zero all 968 MB of attn via the runtime fill path (6.2 TB/s), then
    // overwrite only the ones-bearing rows (265 MB).
    hipMemsetAsync(out + OFF_ATTN, 0,
                   (size_t)BZ * MAXL * MAXL * sizeof(float), stream);
    ones_kernel <<<BZ * 4050, 256, 0, stream>>>(out + OFF_ATTN);
    token_kernel<<<BZ * 1375, 256, 0, stream>>>(input, noise, alphas, out + OFF_TOK, ws);
    mask_kernel <<<(MAXL + 255) / 256, 256, 0, stream>>>(out);
    loss_kernel <<<BZ, 256, 0, stream>>>(ws, alphas, out + OFF_LOSS);
}

// Round 8
// 994.361 us; speedup vs baseline: 1.0879x; 1.0879x over previous
//
#include <hip/hip_runtime.h>
#include <math.h>

// ---- static problem constants ----
#define BZ 8
#define MAXL 5500
#define DD 64
// segment layout:
//   seg0: txt [0,225), img [225,2025)    (src s = L-225)
//   seg1: txt [2025,2250), img [2250,4050) (src s = L-2250+1800)
// attn squares: [0,2025)^2 and [2025,4050)^2

// output offsets (in floats), concatenated in reference return order
#define OFF_LOSS 0
#define OFF_TOK  8
#define OFF_TXT  (8 + BZ * MAXL * DD)          // 2,816,008
#define OFF_IMG  (OFF_TXT + BZ * MAXL)         // 2,860,008
#define OFF_POS  (OFF_IMG + BZ * MAXL)         // 2,904,008
#define OFF_ATTN (OFF_POS + BZ * MAXL * 3)     // 3,036,008  (%4 == 0 -> float4 ok)

// ------------------------------------------------------------------
// 968 MB broadcast attention mask: one block per (b,row), float4 stores.
// ROOFLINE NOTE (rounds 0-7): the timed iteration is one sustained
// pure-write stream -- 3.92 GB harness poison + 0.98 GB outputs at
// ~4.93 TB/s = ~994 us. Five structurally different writers (row-block /
// grid-stride / fill-clone / nt / memset+ones) all land at this limit
// plus their overhead; access pattern is not a lever. The fill kernel's
// profiled 6.2 TB/s is a serialized-replay artifact, not the loop rate.
__global__ __launch_bounds__(256) void attn_kernel(float* __restrict__ attn) {
    int br = blockIdx.x;                 // [0, BZ*MAXL)
    int r = br % MAXL;
    float* row = attn + (size_t)br * MAXL;
    int lo, hi;
    if (r < 2025)      { lo = 0;    hi = 2025; }
    else if (r < 4050) { lo = 2025; hi = 4050; }
    else               { lo = 0;    hi = 0; }
    for (int c4 = threadIdx.x; c4 < MAXL / 4; c4 += 256) {
        int c = c4 * 4;
        float4 v;
        v.x = (c + 0 >= lo && c + 0 < hi) ? 1.f : 0.f;
        v.y = (c + 1 >= lo && c + 1 < hi) ? 1.f : 0.f;
        v.z = (c + 2 >= lo && c + 2 < hi) ? 1.f : 0.f;
        v.w = (c + 3 >= lo && c + 3 < hi) ? 1.f : 0.f;
        reinterpret_cast<float4*>(row)[c4] = v;
    }
}

// ------------------------------------------------------------------
// tokens gather + per-block loss partials. 4 tokens per 256-thread block.
__global__ __launch_bounds__(256) void token_kernel(
        const float* __restrict__ input, const float* __restrict__ noise,
        const float* __restrict__ alphas, float* __restrict__ out_tok,
        float* __restrict__ ws_partial) {
    int blk = blockIdx.x;                 // [0, BZ*1375)
    int b = blk / 1375;
    int Lbase = (blk % 1375) * 4;
    int t = threadIdx.x;
    int L = Lbase + (t >> 6);
    int d = t & 63;

    float tok = 0.f, contrib = 0.f;
    int s = -1;
    if (L >= 225 && L < 2025)       s = L - 225;
    else if (L >= 2250 && L < 4050) s = L - 2250 + 1800;
    if (s >= 0) {
        int g  = b * 3600 + s;
        int tf = g / 900;
        int rr = g - tf * 900;
        int hh = rr / 30;
        int ww = rr - hh * 30;
        int c = d & 15, q = (d >> 4) & 1, p = d >> 5;
        int iidx = ((tf * 16 + c) * 60 + (hh * 2 + p)) * 60 + (ww * 2 + q);
        tok = input[iidx];
        float nz  = noise[((size_t)b * MAXL + L) * DD + d];
        float a   = alphas[b];
        float sig = sqrtf(fmaxf(1.f - a * a, 0.f));
        float diff = tok * (a - 1.f) + nz * sig;
        contrib = diff * diff;
    }
    out_tok[((size_t)b * MAXL + L) * DD + d] = tok;

    // wave64 reduce + cross-wave LDS reduce -> one partial per block
    #pragma unroll
    for (int off = 32; off > 0; off >>= 1)
        contrib += __shfl_down(contrib, off, 64);
    __shared__ float lds[4];
    if ((t & 63) == 0) lds[t >> 6] = contrib;
    __syncthreads();
    if (t == 0) ws_partial[blk] = lds[0] + lds[1] + lds[2] + lds[3];
}

// ------------------------------------------------------------------
// txt/img masks + 3d position ids (tiny)
__global__ __launch_bounds__(256) void mask_kernel(float* __restrict__ out) {
    int L = blockIdx.x * 256 + threadIdx.x;
    if (L >= MAXL) return;
    float txt = ((L < 225) || (L >= 2025 && L < 2250)) ? 1.f : 0.f;
    int tloc = -1;
    if (L >= 225 && L < 2025)       tloc = L - 225;
    else if (L >= 2250 && L < 4050) tloc = L - 2250;   // pos ids reset per segment
    float img = (tloc >= 0) ? 1.f : 0.f;
    float pi = -1.f, pj = -1.f, pk = -1.f;
    if (tloc >= 0) {
        int fi = tloc / 900;
        int rr = tloc - fi * 900;
        pi = (float)fi;
        pj = (float)(rr / 30);
        pk = (float)(rr % 30);
    }
    float* txtp = out + OFF_TXT;
    float* imgp = out + OFF_IMG;
    float* posp = out + OFF_POS;
    #pragma unroll
    for (int b = 0; b < BZ; b++) {
        txtp[b * MAXL + L] = txt;
        imgp[b * MAXL + L] = img;
        posp[((size_t)b * MAXL + L) * 3 + 0] = pi;
        posp[((size_t)b * MAXL + L) * 3 + 1] = pj;
        posp[((size_t)b * MAXL + L) * 3 + 2] = pk;
    }
}

// ------------------------------------------------------------------
// final loss: one block per b sums its 1375 block partials
__global__ __launch_bounds__(256) void loss_kernel(
        const float* __restrict__ ws_partial, const float* __restrict__ alphas,
        float* __restrict__ out_loss) {
    int b = blockIdx.x;
    float s = 0.f;
    for (int i = threadIdx.x; i < 1375; i += 256)
        s += ws_partial[b * 1375 + i];
    #pragma unroll
    for (int off = 32; off > 0; off >>= 1)
        s += __shfl_down(s, off, 64);
    __shared__ float lds[4];
    if ((threadIdx.x & 63) == 0) lds[threadIdx.x >> 6] = s;
    __syncthreads();
    if (threadIdx.x == 0) {
        float tot = lds[0] + lds[1] + lds[2] + lds[3];
        float a = alphas[b];
        out_loss[b] = tot / ((1.f - a * a) * (float)(MAXL * DD));
    }
}

extern "C" void kernel_launch(void* const* d_in, const int* in_sizes, int n_in,
                              void* d_out, int out_size, void* d_ws, size_t ws_size,
                              hipStream_t stream) {
    const float* input  = (const float*)d_in[0];   // (1,32,16,60,60)
    const float* noise  = (const float*)d_in[1];   // (8,5500,64)
    const float* alphas = (const float*)d_in[2];   // (8,)
    float* out = (float*)d_out;
    float* ws  = (float*)d_ws;                     // 11,000 floats used

    attn_kernel <<<BZ * MAXL, 256, 0, stream>>>(out + OFF_ATTN);
    token_kernel<<<BZ * 1375, 256, 0, stream>>>(input, noise, alphas, out + OFF_TOK, ws);
    mask_kernel <<<(MAXL + 255) / 256, 256, 0, stream>>>(out);
    loss_kernel <<<BZ, 256, 0, stream>>>(ws, alphas, out + OFF_LOSS);
}